// Round 7
// baseline (650.195 us; speedup 1.0000x reference)
//
#include <hip/hip_runtime.h>
#include <hip/hip_cooperative_groups.h>
#include <math.h>

namespace cg = cooperative_groups;

typedef float nfloat4 __attribute__((ext_vector_type(4)));  // native vec for nt ops

__device__ inline void nt_store4(const float4 v, float* p) {
    nfloat4 nv = {v.x, v.y, v.z, v.w};
    __builtin_nontemporal_store(nv, (nfloat4*)p);
}

struct KArgs {
    const float *x, *enc_W, *enc_b, *ln_s, *ln_b, *log_dt, *A_re, *A_im,
                *C_re, *C_im, *Dp, *out_W, *out_b, *dec_W, *dec_b,
                *W1, *b1, *g1, *be1, *W2, *b2, *g2, *be2, *W3, *b3;
    float *combined, *parts1, *h1, *parts2, *h2, *out;
};

// acc_row += a.{x,y,z,w} * w{0,1,2,3} (component-wise over 4 j)
#define ACCROW(accv, av)                                        \
    accv.x += av.x*w0.x + av.y*w1.x + av.z*w2.x + av.w*w3.x;    \
    accv.y += av.x*w0.y + av.y*w1.y + av.z*w2.y + av.w*w3.y;    \
    accv.z += av.x*w0.z + av.y*w1.z + av.z*w2.z + av.w*w3.z;    \
    accv.w += av.x*w0.w + av.y*w1.w + av.z*w2.w + av.w*w3.w;

// ---------------------------------------------------------------------------
// S4 front phase body (one block per batch row). smem needs 5120 floats.
// ---------------------------------------------------------------------------
__device__ inline void s4_phase(const KArgs& a, int b, int l, float* smem)
{
    float* Kl  = smem;          // [2][256][4]
    float* xl  = smem + 2048;   // [4][256]
    float* zl  = smem + 3072;   // [256][4]
    float* s4l = smem + 4096;   // [256][4]

    // SSM kernels K[i][m][h], thread m = l
    {
        const float tt = (float)l;
        for (int i = 0; i < 2; ++i) {
            #pragma unroll
            for (int h = 0; h < 4; ++h) {
                float dt = expf(a.log_dt[i*4 + h]);
                float acc = 0.f;
                #pragma unroll
                for (int n = 0; n < 4; ++n) {
                    const int idx = (i*4 + h)*4 + n;
                    float ar = -expf(a.A_re[idx]);
                    float ai = a.A_im[idx];
                    float dr = ar*dt, di = ai*dt;
                    float er  = expf(dr);
                    float e1r = er*cosf(di) - 1.0f;
                    float e1i = er*sinf(di);
                    float inv = 1.0f/(ar*ar + ai*ai);
                    float bdr = (e1r*ar + e1i*ai)*inv;
                    float bdi = (e1i*ar - e1r*ai)*inv;
                    float cr = a.C_re[idx], ci = a.C_im[idx];
                    float cbr = cr*bdr - ci*bdi;
                    float cbi = cr*bdi + ci*bdr;
                    float em = expf(dr*tt);
                    float vr = em*cosf(di*tt);
                    float vi = em*sinf(di*tt);
                    acc += cbr*vr - cbi*vi;
                }
                Kl[(i*256 + l)*4 + h] = 2.0f*acc;
            }
        }
    }

    #pragma unroll
    for (int c = 0; c < 4; ++c)
        xl[c*256 + l] = a.x[(b*4 + c)*256 + l];

    float u[4];
    #pragma unroll
    for (int h = 0; h < 4; ++h) {
        float acc = a.enc_b[h];
        #pragma unroll
        for (int c = 0; c < 4; ++c) acc += xl[c*256 + l]*a.enc_W[c*4 + h];
        u[h] = acc;
    }
    __syncthreads();

    for (int i = 0; i < 2; ++i) {
        float mu = 0.25f*(u[0]+u[1]+u[2]+u[3]);
        float var = 0.f;
        #pragma unroll
        for (int h = 0; h < 4; ++h) { float d = u[h]-mu; var += d*d; }
        var *= 0.25f;
        float rs = rsqrtf(var + 1e-5f);
        float z[4];
        #pragma unroll
        for (int h = 0; h < 4; ++h)
            z[h] = (u[h]-mu)*rs*a.ln_s[i*4 + h] + a.ln_b[i*4 + h];
        *(float4*)&zl[l*4] = make_float4(z[0], z[1], z[2], z[3]);
        __syncthreads();

        float y0 = 0.f, y1 = 0.f, y2 = 0.f, y3 = 0.f;
        const int mlim = l | 63;   // wave-uniform bound
        #pragma unroll 4
        for (int m = 0; m <= mlim; ++m) {
            float4 kk = *(float4*)&Kl[(i*256 + m)*4];
            int p = (l - m) & 255;
            float4 zz = *(float4*)&zl[p*4];
            if (m <= l) {
                y0 += kk.x*zz.x; y1 += kk.y*zz.y;
                y2 += kk.z*zz.z; y3 += kk.w*zz.w;
            }
        }
        float y[4] = {y0, y1, y2, y3};
        #pragma unroll
        for (int h = 0; h < 4; ++h) {
            float v = y[h] + a.Dp[i*4 + h]*z[h];
            float inner = 0.7978845608028654f*(v + 0.044715f*v*v*v);
            y[h] = 0.5f*v*(1.0f + tanhf(inner));
        }
        #pragma unroll
        for (int k = 0; k < 4; ++k) {
            float acc = a.out_b[i*4 + k];
            #pragma unroll
            for (int h = 0; h < 4; ++h) acc += y[h]*a.out_W[(i*4 + h)*4 + k];
            u[k] += acc;
        }
        __syncthreads();
    }

    #pragma unroll
    for (int h = 0; h < 4; ++h) {
        float acc = a.dec_b[h];
        #pragma unroll
        for (int k = 0; k < 4; ++k) acc += u[k]*a.dec_W[k*4 + h];
        s4l[l*4 + h] = acc;
    }
    __syncthreads();

    float* cmb = a.combined + b*1856;
    if (l < 64) {
        int h = l >> 4, kk = l & 15;
        float acc = 0.f;
        #pragma unroll
        for (int j = 0; j < 16; ++j) acc += s4l[(kk*16 + j)*4 + h];
        cmb[l] = acc*(1.0f/16.0f);
    }
    for (int e = l; e < 1792; e += 256) {
        int c = e/448, jj = e%448;
        float v;
        if (jj < 64) {
            v = 0.25f*(xl[c*256 + 4*jj] + xl[c*256 + 4*jj+1] +
                       xl[c*256 + 4*jj+2] + xl[c*256 + 4*jj+3]);
        } else if (jj < 192) {
            int q = jj - 64;
            v = 0.5f*(xl[c*256 + 2*q] + xl[c*256 + 2*q+1]);
        } else {
            v = xl[c*256 + jj - 192];
        }
        cmb[64 + e] = v;
    }
}

// ---------------------------------------------------------------------------
// Partial GEMM tile: M=64 rows, [KCH=64 k-chunk] x [64 j-tile].
// smem needs 64*68 + 64*64 = 8448 floats. Leading barrier protects reuse.
// ---------------------------------------------------------------------------
template<int NCOLS, int ASTRIDE>
__device__ inline void mlp_tile64(const float* __restrict__ A,
                                  const float* __restrict__ W,
                                  float* __restrict__ parts,
                                  int ks, int jt, int t, float* smem)
{
    constexpr int KCH = 64, APAD = 68;
    float* At = smem;              // [64][68]
    float* Wl = smem + 64*APAD;    // [64][64]
    const int k0 = ks*KCH, j0 = jt*64;
    __syncthreads();               // protect LDS reuse from previous phase/iter
    #pragma unroll
    for (int f = t; f < 64*16; f += 256) {       // A: 16 float4 per row
        const int row = f >> 4, c4 = f & 15;
        *(float4*)&At[row*APAD + c4*4] =
            *(const float4*)(A + (size_t)row*ASTRIDE + k0 + c4*4);
    }
    #pragma unroll
    for (int f = t; f < KCH*16; f += 256) {      // W: 16 float4 per row
        const int row = f >> 4, c4 = f & 15;
        *(float4*)&Wl[row*64 + c4*4] =
            *(const float4*)(W + (size_t)(k0 + row)*NCOLS + j0 + c4*4);
    }
    __syncthreads();
    const int ji = t & 15, br = (t >> 4)*4;
    float4 acc0={0,0,0,0}, acc1={0,0,0,0}, acc2={0,0,0,0}, acc3={0,0,0,0};
    #pragma unroll 4
    for (int k4 = 0; k4 < KCH; k4 += 4) {
        float4 w0 = *(float4*)&Wl[(k4+0)*64 + ji*4];
        float4 w1 = *(float4*)&Wl[(k4+1)*64 + ji*4];
        float4 w2 = *(float4*)&Wl[(k4+2)*64 + ji*4];
        float4 w3 = *(float4*)&Wl[(k4+3)*64 + ji*4];
        float4 a0 = *(float4*)&At[(br+0)*APAD + k4];
        float4 a1 = *(float4*)&At[(br+1)*APAD + k4];
        float4 a2 = *(float4*)&At[(br+2)*APAD + k4];
        float4 a3 = *(float4*)&At[(br+3)*APAD + k4];
        ACCROW(acc0, a0) ACCROW(acc1, a1) ACCROW(acc2, a2) ACCROW(acc3, a3)
    }
    float* pbase = parts + (size_t)(ks*64 + br)*NCOLS + j0 + ji*4;
    *(float4*)(pbase)           = acc0;
    *(float4*)(pbase + NCOLS)   = acc1;
    *(float4*)(pbase + 2*NCOLS) = acc2;
    *(float4*)(pbase + 3*NCOLS) = acc3;
}

// ---------------------------------------------------------------------------
// Sum partials + bias, LayerNorm + ReLU (one block per batch row).
// ---------------------------------------------------------------------------
template<int N>
__device__ inline void reduce_ln_phase(const float* __restrict__ parts,
    const float* __restrict__ bias, const float* __restrict__ g,
    const float* __restrict__ be, float* __restrict__ out,
    int KS, int b, int t, float* smem)
{
    constexpr int NV = N/1024;
    float4 acc[NV];
    #pragma unroll
    for (int v = 0; v < NV; ++v)
        acc[v] = *(const float4*)(bias + v*1024 + t*4);
    for (int ks = 0; ks < KS; ++ks) {
        const float* p = parts + (size_t)(ks*64 + b)*N;
        #pragma unroll
        for (int v = 0; v < NV; ++v) {
            float4 q = *(const float4*)(p + v*1024 + t*4);
            acc[v].x += q.x; acc[v].y += q.y; acc[v].z += q.z; acc[v].w += q.w;
        }
    }
    float s = 0.f, s2 = 0.f;
    #pragma unroll
    for (int v = 0; v < NV; ++v) {
        s  += acc[v].x + acc[v].y + acc[v].z + acc[v].w;
        s2 += acc[v].x*acc[v].x + acc[v].y*acc[v].y +
              acc[v].z*acc[v].z + acc[v].w*acc[v].w;
    }
    #pragma unroll
    for (int off = 32; off > 0; off >>= 1) {
        s  += __shfl_down(s,  off);
        s2 += __shfl_down(s2, off);
    }
    __syncthreads();               // protect smem reuse
    const int w = t >> 6;
    if ((t & 63) == 0) { smem[w] = s; smem[4 + w] = s2; }
    __syncthreads();
    float ts  = smem[0] + smem[1] + smem[2] + smem[3];
    float ts2 = smem[4] + smem[5] + smem[6] + smem[7];
    const float inv_n = 1.0f/(float)N;
    float mu  = ts*inv_n;
    float var = ts2*inv_n - mu*mu;
    float rs  = rsqrtf(var + 1e-5f);
    #pragma unroll
    for (int v = 0; v < NV; ++v) {
        const int j = v*1024 + t*4;
        float4 gv  = *(const float4*)(g + j);
        float4 bev = *(const float4*)(be + j);
        float4 o;
        o.x = fmaxf((acc[v].x - mu)*rs*gv.x + bev.x, 0.f);
        o.y = fmaxf((acc[v].y - mu)*rs*gv.y + bev.y, 0.f);
        o.z = fmaxf((acc[v].z - mu)*rs*gv.z + bev.z, 0.f);
        o.w = fmaxf((acc[v].w - mu)*rs*gv.w + bev.w, 0.f);
        *(float4*)(out + (size_t)b*N + j) = o;
    }
}

// ---------------------------------------------------------------------------
// Cooperative persistent kernel: all 6 stages, grid.sync() between.
// grid = 512 x 256. Static LDS = 8448 floats = 33,792 B (2+ blocks/CU).
// ---------------------------------------------------------------------------
#define SMEM_F 8448

__global__ __launch_bounds__(256, 2) void mega(KArgs a)
{
    __shared__ float smem[SMEM_F];
    cg::grid_group grid = cg::this_grid();
    const int blk = blockIdx.x;
    const int t   = threadIdx.x;

    // P0: S4 front (blocks 0..63)
    if (blk < 64) s4_phase(a, blk, t, smem);
    __threadfence();
    grid.sync();

    // P1: mlp1 partial GEMM: 29 ks x 16 jt = 464 tiles
    if (blk < 464)
        mlp_tile64<1024, 1856>(a.combined, a.W1, a.parts1,
                               blk % 29, blk / 29, t, smem);
    __threadfence();
    grid.sync();

    // P2: reduce + LN + ReLU -> h1 (blocks 0..63)
    if (blk < 64)
        reduce_ln_phase<1024>(a.parts1, a.b1, a.g1, a.be1, a.h1, 29, blk, t, smem);
    __threadfence();
    grid.sync();

    // P3: mlp2 partial GEMM: 16 ks x 64 jt = 1024 tiles, 2 per block
    #pragma unroll
    for (int it = 0; it < 2; ++it) {
        const int tile = blk + it*512;
        mlp_tile64<4096, 1024>(a.h1, a.W2, a.parts2,
                               tile & 15, tile >> 4, t, smem);
    }
    __threadfence();
    grid.sync();

    // P4: reduce + LN + ReLU -> h2 (blocks 0..63)
    if (blk < 64)
        reduce_ln_phase<4096>(a.parts2, a.b2, a.g2, a.be2, a.h2, 16, blk, t, smem);
    __threadfence();
    grid.sync();

    // P5: final matmul -> out [64,512,4096]; block rg owns rows rg*64..+63
    {
        const int rg  = blk;
        const int bs0 = rg*64;
        float* h_lds = smem;   // 512 floats
        __syncthreads();
        for (int e = t; e < 512; e += 256)
            h_lds[e] = a.h2[(size_t)rg*512 + e];   // vector loads (coherent path)
        __syncthreads();
        for (int js = 0; js < 4; ++js) {
            const int j = js*1024 + t*4;
            float4 w[8];
            #pragma unroll
            for (int k = 0; k < 8; ++k)
                w[k] = *(const float4*)(a.W3 + k*4096 + j);
            const float4 bv = *(const float4*)(a.b3 + j);
            float* __restrict__ obase = a.out + (size_t)bs0*4096 + j;
            #pragma unroll 4
            for (int r = 0; r < 64; ++r) {
                float4 acc = bv;
                #pragma unroll
                for (int k = 0; k < 8; ++k) {
                    const float hv = h_lds[r*8 + k];
                    acc.x += hv*w[k].x; acc.y += hv*w[k].y;
                    acc.z += hv*w[k].z; acc.w += hv*w[k].w;
                }
                nt_store4(acc, obase + (size_t)r*4096);
            }
        }
    }
}

// ===========================================================================
// Fallback path: the proven 6-kernel pipeline (round-5, 187.7 us).
// ===========================================================================
__global__ __launch_bounds__(256) void s4front(KArgs a)
{
    __shared__ float smem[5120];
    s4_phase(a, blockIdx.x, threadIdx.x, smem);
}

template<int NCOLS, int ASTRIDE, int KCH>
__global__ __launch_bounds__(256) void mlp_part(
    const float* __restrict__ A, const float* __restrict__ W,
    float* __restrict__ parts)
{
    __shared__ float At[64][KCH + 4];
    __shared__ float Wl[KCH][64];
    const int ks = blockIdx.x, k0 = ks*KCH;
    const int j0 = blockIdx.y*64;
    const int t  = threadIdx.x;
    constexpr int AF4 = 64*KCH/4, RF4 = KCH/4;
    #pragma unroll
    for (int f = t; f < AF4; f += 256) {
        const int row = f / RF4, c4 = f % RF4;
        *(float4*)&At[row][c4*4] =
            *(const float4*)(A + (size_t)row*ASTRIDE + k0 + c4*4);
    }
    constexpr int WF4 = KCH*16;
    #pragma unroll
    for (int f = t; f < WF4; f += 256) {
        const int row = f >> 4, c4 = f & 15;
        *(float4*)&Wl[row][c4*4] =
            *(const float4*)(W + (size_t)(k0 + row)*NCOLS + j0 + c4*4);
    }
    __syncthreads();
    const int ji = t & 15, br = (t >> 4)*4;
    float4 acc0={0,0,0,0}, acc1={0,0,0,0}, acc2={0,0,0,0}, acc3={0,0,0,0};
    #pragma unroll 4
    for (int k4 = 0; k4 < KCH; k4 += 4) {
        float4 w0 = *(float4*)&Wl[k4+0][ji*4];
        float4 w1 = *(float4*)&Wl[k4+1][ji*4];
        float4 w2 = *(float4*)&Wl[k4+2][ji*4];
        float4 w3 = *(float4*)&Wl[k4+3][ji*4];
        float4 a0 = *(float4*)&At[br+0][k4];
        float4 a1 = *(float4*)&At[br+1][k4];
        float4 a2 = *(float4*)&At[br+2][k4];
        float4 a3 = *(float4*)&At[br+3][k4];
        ACCROW(acc0, a0) ACCROW(acc1, a1) ACCROW(acc2, a2) ACCROW(acc3, a3)
    }
    float* pbase = parts + (size_t)(ks*64 + br)*NCOLS + j0 + ji*4;
    *(float4*)(pbase)           = acc0;
    *(float4*)(pbase + NCOLS)   = acc1;
    *(float4*)(pbase + 2*NCOLS) = acc2;
    *(float4*)(pbase + 3*NCOLS) = acc3;
}

template<int N>
__global__ __launch_bounds__(256) void reduce_ln_relu(
    const float* __restrict__ parts, const float* __restrict__ bias,
    const float* __restrict__ g, const float* __restrict__ be,
    float* __restrict__ out, int KS)
{
    __shared__ float smem[8];
    reduce_ln_phase<N>(parts, bias, g, be, out, KS, blockIdx.x, threadIdx.x, smem);
}

__global__ __launch_bounds__(256) void final_mm(
    const float* __restrict__ h2, const float* __restrict__ W3,
    const float* __restrict__ b3, float* __restrict__ out)
{
    const int rg = blockIdx.x, js = blockIdx.y, t = threadIdx.x;
    const int bs0 = rg*64;
    const int j = js*1024 + t*4;
    float4 w[8];
    #pragma unroll
    for (int k = 0; k < 8; ++k) w[k] = *(const float4*)(W3 + k*4096 + j);
    const float4 bv = *(const float4*)(b3 + j);
    const float* __restrict__ hrow = h2 + (size_t)bs0*8;
    float* __restrict__ obase = out + (size_t)bs0*4096 + j;
    #pragma unroll 4
    for (int r = 0; r < 64; ++r) {
        float4 acc = bv;
        #pragma unroll
        for (int k = 0; k < 8; ++k) {
            const float hv = hrow[r*8 + k];   // wave-uniform -> s_load
            acc.x += hv*w[k].x; acc.y += hv*w[k].y;
            acc.z += hv*w[k].z; acc.w += hv*w[k].w;
        }
        nt_store4(acc, obase + (size_t)r*4096);
    }
}

// ---------------------------------------------------------------------------
extern "C" void kernel_launch(void* const* d_in, const int* in_sizes, int n_in,
                              void* d_out, int out_size, void* d_ws, size_t ws_size,
                              hipStream_t stream) {
    KArgs a;
    a.x      = (const float*)d_in[0];
    a.enc_W  = (const float*)d_in[1];
    a.enc_b  = (const float*)d_in[2];
    a.ln_s   = (const float*)d_in[3];
    a.ln_b   = (const float*)d_in[4];
    a.log_dt = (const float*)d_in[5];
    a.A_re   = (const float*)d_in[6];
    a.A_im   = (const float*)d_in[7];
    a.C_re   = (const float*)d_in[8];
    a.C_im   = (const float*)d_in[9];
    a.Dp     = (const float*)d_in[10];
    a.out_W  = (const float*)d_in[11];
    a.out_b  = (const float*)d_in[12];
    a.dec_W  = (const float*)d_in[13];
    a.dec_b  = (const float*)d_in[14];
    a.W1     = (const float*)d_in[15];
    a.b1     = (const float*)d_in[16];
    a.g1     = (const float*)d_in[17];
    a.be1    = (const float*)d_in[18];
    a.W2     = (const float*)d_in[19];
    a.b2     = (const float*)d_in[20];
    a.g2     = (const float*)d_in[21];
    a.be2    = (const float*)d_in[22];
    a.W3     = (const float*)d_in[23];
    a.b3     = (const float*)d_in[24];

    float* ws = (float*)d_ws;
    a.combined = ws;                          // 64*1856
    a.parts1   = a.combined + 64*1856;        // 29*64*1024
    a.h1       = a.parts1 + 29*64*1024;       // 64*1024
    a.parts2   = a.h1 + 64*1024;              // 16*64*4096 (mega) / 8 slices (fallback)
    a.h2       = a.parts2 + 16*64*4096;       // 64*4096
    a.out      = (float*)d_out;

    // Capture-safe occupancy check: need >=2 blocks/CU for 512 co-resident.
    int nb = 0;
    hipError_t qerr = hipOccupancyMaxActiveBlocksPerMultiprocessor(
        &nb, reinterpret_cast<const void*>(&mega), 256, 0);
    if (qerr == hipSuccess && nb >= 2) {
        void* params[] = { (void*)&a };
        hipError_t lerr = hipLaunchCooperativeKernel(
            reinterpret_cast<void*>(&mega), dim3(512), dim3(256),
            params, 0, stream);
        if (lerr == hipSuccess) return;
    }

    // Fallback: proven 6-kernel pipeline.
    s4front<<<64, 256, 0, stream>>>(a);
    mlp_part<1024,1856,64><<<dim3(29,16), 256, 0, stream>>>(a.combined, a.W1, a.parts1);
    reduce_ln_relu<1024><<<64, 256, 0, stream>>>(a.parts1, a.b1, a.g1, a.be1, a.h1, 29);
    mlp_part<4096,1024,128><<<dim3(8,64), 256, 0, stream>>>(a.h1, a.W2, a.parts2);
    reduce_ln_relu<4096><<<64, 256, 0, stream>>>(a.parts2, a.b2, a.g2, a.be2, a.h2, 8);
    final_mm<<<dim3(512,4), 256, 0, stream>>>(a.h2, a.W3, a.b3, a.out);
}

// Round 8
// 374.074 us; speedup vs baseline: 1.7381x; 1.7381x over previous
//
#include <hip/hip_runtime.h>
#include <hip/hip_bf16.h>
#include <math.h>

// Problem constants
#define BDEF 64
#define LSEQ 256
#define HD   4
#define NST  4
#define NBLK 2

typedef float nfloat4 __attribute__((ext_vector_type(4)));  // native vec for nt ops

__device__ inline void nt_store4(const float4 v, float* p) {
    nfloat4 nv = {v.x, v.y, v.z, v.w};
    __builtin_nontemporal_store(nv, (nfloat4*)p);
}

// ---------------------------------------------------------------------------
// Kernel 1: K-comp + encoder + 2x S4D block + decoder + pooling
//           -> combined [64,1856].  grid=64 (one block per batch), block=256.
// ---------------------------------------------------------------------------
__global__ __launch_bounds__(256) void s4front(
    const float* __restrict__ x, const float* __restrict__ enc_W,
    const float* __restrict__ enc_b, const float* __restrict__ ln_s,
    const float* __restrict__ ln_b, const float* __restrict__ log_dt,
    const float* __restrict__ A_re, const float* __restrict__ A_im,
    const float* __restrict__ C_re, const float* __restrict__ C_im,
    const float* __restrict__ Dp, const float* __restrict__ out_W,
    const float* __restrict__ out_b, const float* __restrict__ dec_W,
    const float* __restrict__ dec_b, float* __restrict__ combined)
{
    const int b = blockIdx.x;
    const int l = threadIdx.x;
    __shared__ float Kl[NBLK][LSEQ][4];   // conv kernels, 8 KB
    __shared__ float x_lds[4][256];       // raw input row
    __shared__ float z_lds[256][4];       // pre-conv activations ([l][h], b128)
    __shared__ float s4_lds[256][4];      // decoder output for pooling

    // ---- compute SSM kernels K[i][m][h] (thread m = l) ----
    {
        const float t = (float)l;
        for (int i = 0; i < NBLK; ++i) {
            #pragma unroll
            for (int h = 0; h < HD; ++h) {
                float dt = expf(log_dt[i*HD + h]);
                float acc = 0.f;
                #pragma unroll
                for (int n = 0; n < NST; ++n) {
                    const int idx = (i*HD + h)*NST + n;
                    float ar = -expf(A_re[idx]);     // Re(A)
                    float ai = A_im[idx];            // Im(A)
                    float dr = ar*dt, di = ai*dt;    // dtA
                    float er  = expf(dr);            // Bd = (exp(dtA)-1)/A
                    float e1r = er*cosf(di) - 1.0f;
                    float e1i = er*sinf(di);
                    float inv = 1.0f/(ar*ar + ai*ai);
                    float bdr = (e1r*ar + e1i*ai)*inv;
                    float bdi = (e1i*ar - e1r*ai)*inv;
                    float cr = C_re[idx], ci = C_im[idx];
                    float cbr = cr*bdr - ci*bdi;     // C*Bd
                    float cbi = cr*bdi + ci*bdr;
                    float em = expf(dr*t);           // vand = exp(dtA*t)
                    float vr = em*cosf(di*t);
                    float vi = em*sinf(di*t);
                    acc += cbr*vr - cbi*vi;
                }
                Kl[i][l][h] = 2.0f*acc;
            }
        }
    }

    #pragma unroll
    for (int c = 0; c < 4; ++c)
        x_lds[c][l] = x[(b*4 + c)*256 + l];

    // encoder: u[h] = sum_c x[c,l]*enc_W[c,h] + enc_b[h]
    float u[4];
    #pragma unroll
    for (int h = 0; h < 4; ++h) {
        float a = enc_b[h];
        #pragma unroll
        for (int c = 0; c < 4; ++c) a += x_lds[c][l]*enc_W[c*4 + h];
        u[h] = a;
    }
    __syncthreads();

    for (int i = 0; i < NBLK; ++i) {
        // prenorm LN over H=4
        float mu = 0.25f*(u[0]+u[1]+u[2]+u[3]);
        float var = 0.f;
        #pragma unroll
        for (int h = 0; h < 4; ++h) { float d = u[h]-mu; var += d*d; }
        var *= 0.25f;
        float rs = rsqrtf(var + 1e-5f);
        float z[4];
        #pragma unroll
        for (int h = 0; h < 4; ++h)
            z[h] = (u[h]-mu)*rs*ln_s[i*4 + h] + ln_b[i*4 + h];
        *(float4*)&z_lds[l][0] = make_float4(z[0], z[1], z[2], z[3]);
        __syncthreads();

        // causal convolution: y[h] = sum_{m<=l} K[i][m][h]*z[l-m][h]
        float y0 = 0.f, y1 = 0.f, y2 = 0.f, y3 = 0.f;
        const int mlim = l | 63;   // wave-uniform upper bound
        #pragma unroll 4
        for (int m = 0; m <= mlim; ++m) {
            float4 kk = *(const float4*)&Kl[i][m][0];  // uniform -> broadcast
            int p = (l - m) & 255;                     // safe wrap (masked tail)
            float4 zz = *(const float4*)&z_lds[p][0];
            if (m <= l) {
                y0 += kk.x*zz.x; y1 += kk.y*zz.y;
                y2 += kk.z*zz.z; y3 += kk.w*zz.w;
            }
        }
        float y[4] = {y0, y1, y2, y3};
        // skip + gelu (tanh approximation, jax.nn.gelu default)
        #pragma unroll
        for (int h = 0; h < 4; ++h) {
            float v = y[h] + Dp[i*4 + h]*z[h];
            float inner = 0.7978845608028654f*(v + 0.044715f*v*v*v);
            y[h] = 0.5f*v*(1.0f + tanhf(inner));
        }
        // output projection over h + residual
        #pragma unroll
        for (int k = 0; k < 4; ++k) {
            float a = out_b[i*4 + k];
            #pragma unroll
            for (int h = 0; h < 4; ++h) a += y[h]*out_W[(i*4 + h)*4 + k];
            u[k] += a;
        }
        __syncthreads();   // protect z_lds before next iteration overwrite
    }

    // decoder
    #pragma unroll
    for (int h = 0; h < 4; ++h) {
        float a = dec_b[h];
        #pragma unroll
        for (int k = 0; k < 4; ++k) a += u[k]*dec_W[k*4 + h];
        s4_lds[l][h] = a;
    }
    __syncthreads();

    float* cmb = combined + b*1856;
    // z16: [4,16] pooled (window 16), flattened h*16+k
    if (l < 64) {
        int h = l >> 4, kk = l & 15;
        float a = 0.f;
        #pragma unroll
        for (int j = 0; j < 16; ++j) a += s4_lds[kk*16 + j][h];
        cmb[l] = a*(1.0f/16.0f);
    }
    // fpp: [4,448] = concat(pool64(win4), pool128(win2), raw256), offset 64
    for (int e = l; e < 1792; e += 256) {
        int c = e/448, jj = e%448;
        float v;
        if (jj < 64) {
            v = 0.25f*(x_lds[c][4*jj] + x_lds[c][4*jj+1] +
                       x_lds[c][4*jj+2] + x_lds[c][4*jj+3]);
        } else if (jj < 192) {
            int q = jj - 64;
            v = 0.5f*(x_lds[c][2*q] + x_lds[c][2*q+1]);
        } else {
            v = x_lds[c][jj - 192];
        }
        cmb[64 + e] = v;
    }
}

// ---------------------------------------------------------------------------
// Kernel 2/4: partial GEMM, M=64 fixed. Block = [KCH k-chunk] x [64 j-tile],
// writes parts[ks][64][NCOLS]. grid = (K/KCH, NCOLS/64), block 256.
// ---------------------------------------------------------------------------
template<int NCOLS, int ASTRIDE, int KCH>
__global__ __launch_bounds__(256) void mlp_part(
    const float* __restrict__ A, const float* __restrict__ W,
    float* __restrict__ parts)
{
    __shared__ float At[64][KCH + 4];  // A chunk, [b][k], padded
    __shared__ float Wl[KCH][64];      // W tile [k][j]
    const int ks = blockIdx.x, k0 = ks*KCH;
    const int j0 = blockIdx.y*64;
    const int t  = threadIdx.x;

    {
        constexpr int AF4 = 64*KCH/4;
        constexpr int RF4 = KCH/4;
        #pragma unroll
        for (int f = t; f < AF4; f += 256) {
            const int row = f / RF4, c4 = f % RF4;
            *(float4*)&At[row][c4*4] =
                *(const float4*)(A + (size_t)row*ASTRIDE + k0 + c4*4);
        }
        constexpr int WF4 = KCH*16;
        #pragma unroll
        for (int f = t; f < WF4; f += 256) {
            const int row = f >> 4, c4 = f & 15;
            *(float4*)&Wl[row][c4*4] =
                *(const float4*)(W + (size_t)(k0 + row)*NCOLS + j0 + c4*4);
        }
    }
    __syncthreads();

    const int bi = t >> 4, ji = t & 15;
    const int br = bi*4;
    float4 acc0 = {0,0,0,0}, acc1 = {0,0,0,0}, acc2 = {0,0,0,0}, acc3 = {0,0,0,0};
    #pragma unroll 8
    for (int k = 0; k < KCH; ++k) {
        float4 wv = *(const float4*)&Wl[k][ji*4];
        float a0 = At[br+0][k], a1 = At[br+1][k];
        float a2 = At[br+2][k], a3 = At[br+3][k];
        acc0.x += a0*wv.x; acc0.y += a0*wv.y; acc0.z += a0*wv.z; acc0.w += a0*wv.w;
        acc1.x += a1*wv.x; acc1.y += a1*wv.y; acc1.z += a1*wv.z; acc1.w += a1*wv.w;
        acc2.x += a2*wv.x; acc2.y += a2*wv.y; acc2.z += a2*wv.z; acc2.w += a2*wv.w;
        acc3.x += a3*wv.x; acc3.y += a3*wv.y; acc3.z += a3*wv.z; acc3.w += a3*wv.w;
    }
    float* pbase = parts + (size_t)(ks*64 + br)*NCOLS + j0 + ji*4;
    *(float4*)(pbase)             = acc0;
    *(float4*)(pbase + NCOLS)     = acc1;
    *(float4*)(pbase + 2*NCOLS)   = acc2;
    *(float4*)(pbase + 3*NCOLS)   = acc3;
}

// ---------------------------------------------------------------------------
// Kernel 3/5: sum partials + bias, then LayerNorm + ReLU.  grid=64 (per b).
// ---------------------------------------------------------------------------
template<int N>
__global__ __launch_bounds__(256) void reduce_ln_relu(
    const float* __restrict__ parts, const float* __restrict__ bias,
    const float* __restrict__ g, const float* __restrict__ be,
    float* __restrict__ out, int KS)
{
    constexpr int NV = N/1024;      // float4 per thread
    const int b = blockIdx.x, t = threadIdx.x;
    float4 acc[NV];
    #pragma unroll
    for (int v = 0; v < NV; ++v)
        acc[v] = *(const float4*)(bias + v*1024 + t*4);
    for (int ks = 0; ks < KS; ++ks) {
        const float* p = parts + (size_t)(ks*64 + b)*N;
        #pragma unroll
        for (int v = 0; v < NV; ++v) {
            float4 q = *(const float4*)(p + v*1024 + t*4);
            acc[v].x += q.x; acc[v].y += q.y; acc[v].z += q.z; acc[v].w += q.w;
        }
    }
    float s = 0.f, s2 = 0.f;
    #pragma unroll
    for (int v = 0; v < NV; ++v) {
        s  += acc[v].x + acc[v].y + acc[v].z + acc[v].w;
        s2 += acc[v].x*acc[v].x + acc[v].y*acc[v].y +
              acc[v].z*acc[v].z + acc[v].w*acc[v].w;
    }
    #pragma unroll
    for (int off = 32; off > 0; off >>= 1) {
        s  += __shfl_down(s,  off);
        s2 += __shfl_down(s2, off);
    }
    __shared__ float red[2][4];
    const int w = t >> 6;
    if ((t & 63) == 0) { red[0][w] = s; red[1][w] = s2; }
    __syncthreads();
    float ts  = red[0][0] + red[0][1] + red[0][2] + red[0][3];
    float ts2 = red[1][0] + red[1][1] + red[1][2] + red[1][3];
    const float inv_n = 1.0f/(float)N;
    float mu  = ts*inv_n;
    float var = ts2*inv_n - mu*mu;
    float rs  = rsqrtf(var + 1e-5f);
    #pragma unroll
    for (int v = 0; v < NV; ++v) {
        const int j = v*1024 + t*4;
        float4 gv  = *(const float4*)(g + j);
        float4 bev = *(const float4*)(be + j);
        float4 o;
        o.x = fmaxf((acc[v].x - mu)*rs*gv.x + bev.x, 0.f);
        o.y = fmaxf((acc[v].y - mu)*rs*gv.y + bev.y, 0.f);
        o.z = fmaxf((acc[v].z - mu)*rs*gv.z + bev.z, 0.f);
        o.w = fmaxf((acc[v].w - mu)*rs*gv.w + bev.w, 0.f);
        *(float4*)(out + (size_t)b*N + j) = o;
    }
}

// ---------------------------------------------------------------------------
// Kernel 6: out[b,s,:] = h2[b, s*8 .. s*8+7] @ W3 + b3 -> [64,512,4096] f32
// grid = (512 row-groups of 64 rows, 4 j-slices of 1024), block 256.
// h2 reads are wave-uniform -> scalar-cache s_load path; no LDS, no barrier.
// ---------------------------------------------------------------------------
#define ROWS_D 64
__global__ __launch_bounds__(256) void final_mm(
    const float* __restrict__ h2, const float* __restrict__ W3,
    const float* __restrict__ b3, float* __restrict__ out)
{
    const int rg = blockIdx.x;
    const int js = blockIdx.y;
    const int t  = threadIdx.x;
    const int bs0 = rg*ROWS_D;
    const int j = js*1024 + t*4;
    float4 w[8];
    #pragma unroll
    for (int k = 0; k < 8; ++k) w[k] = *(const float4*)(W3 + k*4096 + j);
    const float4 bv = *(const float4*)(b3 + j);
    const float* __restrict__ hrow = h2 + (size_t)bs0*8;
    float* __restrict__ obase = out + (size_t)bs0*4096 + j;
    #pragma unroll 4
    for (int r = 0; r < ROWS_D; ++r) {
        float4 acc = bv;
        #pragma unroll
        for (int k = 0; k < 8; ++k) {
            const float hv = hrow[r*8 + k];   // wave-uniform -> s_load (K$)
            acc.x += hv*w[k].x; acc.y += hv*w[k].y;
            acc.z += hv*w[k].z; acc.w += hv*w[k].w;
        }
        nt_store4(acc, obase + (size_t)r*4096);
    }
}

// ---------------------------------------------------------------------------
extern "C" void kernel_launch(void* const* d_in, const int* in_sizes, int n_in,
                              void* d_out, int out_size, void* d_ws, size_t ws_size,
                              hipStream_t stream) {
    const float* x      = (const float*)d_in[0];
    const float* enc_W  = (const float*)d_in[1];
    const float* enc_b  = (const float*)d_in[2];
    const float* ln_s   = (const float*)d_in[3];
    const float* ln_b   = (const float*)d_in[4];
    const float* log_dt = (const float*)d_in[5];
    const float* A_re   = (const float*)d_in[6];
    const float* A_im   = (const float*)d_in[7];
    const float* C_re   = (const float*)d_in[8];
    const float* C_im   = (const float*)d_in[9];
    const float* Dp     = (const float*)d_in[10];
    const float* out_W  = (const float*)d_in[11];
    const float* out_b  = (const float*)d_in[12];
    const float* dec_W  = (const float*)d_in[13];
    const float* dec_b  = (const float*)d_in[14];
    const float* W1     = (const float*)d_in[15];
    const float* b1     = (const float*)d_in[16];
    const float* g1     = (const float*)d_in[17];
    const float* be1    = (const float*)d_in[18];
    const float* W2     = (const float*)d_in[19];
    const float* b2     = (const float*)d_in[20];
    const float* g2     = (const float*)d_in[21];
    const float* be2    = (const float*)d_in[22];
    const float* W3     = (const float*)d_in[23];
    const float* b3     = (const float*)d_in[24];
    float* out = (float*)d_out;

    float* ws = (float*)d_ws;
    float* combined = ws;                        // 64*1856
    float* parts1   = combined + 64*1856;        // 29*64*1024
    float* h1       = parts1 + 29*64*1024;       // 64*1024
    float* parts2   = h1 + 64*1024;              // 8*64*4096
    float* h2       = parts2 + 8*64*4096;        // 64*4096

    s4front<<<64, 256, 0, stream>>>(x, enc_W, enc_b, ln_s, ln_b, log_dt,
                                    A_re, A_im, C_re, C_im, Dp,
                                    out_W, out_b, dec_W, dec_b, combined);
    mlp_part<1024,1856,64><<<dim3(29,16), 256, 0, stream>>>(combined, W1, parts1);
    reduce_ln_relu<1024><<<64, 256, 0, stream>>>(parts1, b1, g1, be1, h1, 29);
    mlp_part<4096,1024,128><<<dim3(8,64), 256, 0, stream>>>(h1, W2, parts2);
    reduce_ln_relu<4096><<<64, 256, 0, stream>>>(parts2, b2, g2, be2, h2, 8);
    final_mm<<<dim3(512,4), 256, 0, stream>>>(h2, W3, b3, out);
    // --- MEASUREMENT: two extra idempotent final_mm dispatches. ---
    // dur_us = base(187.7) + 2*F  =>  F = (dur - 187.7)/2. Output unchanged.
    final_mm<<<dim3(512,4), 256, 0, stream>>>(h2, W3, b3, out);
    final_mm<<<dim3(512,4), 256, 0, stream>>>(h2, W3, b3, out);
}

// Round 9
// 208.612 us; speedup vs baseline: 3.1168x; 1.7932x over previous
//
#include <hip/hip_runtime.h>
#include <hip/hip_bf16.h>
#include <math.h>

// Problem constants
#define BDEF 64
#define LSEQ 256
#define HD   4
#define NST  4
#define NBLK 2

typedef float nfloat4 __attribute__((ext_vector_type(4)));

__device__ inline float lane_bcast(float v, int lane) {
    return __int_as_float(__builtin_amdgcn_readlane(__float_as_int(v), lane));
}

// acc_row += a.{x,y,z,w} * w{0,1,2,3}
#define ACCROW(accv, av)                                        \
    accv.x += av.x*w0.x + av.y*w1.x + av.z*w2.x + av.w*w3.x;    \
    accv.y += av.x*w0.y + av.y*w1.y + av.z*w2.y + av.w*w3.y;    \
    accv.z += av.x*w0.z + av.y*w1.z + av.z*w2.z + av.w*w3.z;    \
    accv.w += av.x*w0.w + av.y*w1.w + av.z*w2.w + av.w*w3.w;

// ---------------------------------------------------------------------------
// Kernel 1: K-comp + encoder + 2x S4D block + decoder + pooling
//           -> combined [64,1856].  grid=64, block=256.
// ---------------------------------------------------------------------------
__global__ __launch_bounds__(256) void s4front(
    const float* __restrict__ x, const float* __restrict__ enc_W,
    const float* __restrict__ enc_b, const float* __restrict__ ln_s,
    const float* __restrict__ ln_b, const float* __restrict__ log_dt,
    const float* __restrict__ A_re, const float* __restrict__ A_im,
    const float* __restrict__ C_re, const float* __restrict__ C_im,
    const float* __restrict__ Dp, const float* __restrict__ out_W,
    const float* __restrict__ out_b, const float* __restrict__ dec_W,
    const float* __restrict__ dec_b, float* __restrict__ combined)
{
    const int b = blockIdx.x;
    const int l = threadIdx.x;
    __shared__ float Kl[NBLK][LSEQ][4];
    __shared__ float x_lds[4][256];
    __shared__ float z_lds[256][4];
    __shared__ float s4_lds[256][4];

    {
        const float t = (float)l;
        for (int i = 0; i < NBLK; ++i) {
            #pragma unroll
            for (int h = 0; h < HD; ++h) {
                float dt = expf(log_dt[i*HD + h]);
                float acc = 0.f;
                #pragma unroll
                for (int n = 0; n < NST; ++n) {
                    const int idx = (i*HD + h)*NST + n;
                    float ar = -expf(A_re[idx]);
                    float ai = A_im[idx];
                    float dr = ar*dt, di = ai*dt;
                    float er  = expf(dr);
                    float e1r = er*cosf(di) - 1.0f;
                    float e1i = er*sinf(di);
                    float inv = 1.0f/(ar*ar + ai*ai);
                    float bdr = (e1r*ar + e1i*ai)*inv;
                    float bdi = (e1i*ar - e1r*ai)*inv;
                    float cr = C_re[idx], ci = C_im[idx];
                    float cbr = cr*bdr - ci*bdi;
                    float cbi = cr*bdi + ci*bdr;
                    float em = expf(dr*t);
                    float vr = em*cosf(di*t);
                    float vi = em*sinf(di*t);
                    acc += cbr*vr - cbi*vi;
                }
                Kl[i][l][h] = 2.0f*acc;
            }
        }
    }

    #pragma unroll
    for (int c = 0; c < 4; ++c)
        x_lds[c][l] = x[(b*4 + c)*256 + l];

    float u[4];
    #pragma unroll
    for (int h = 0; h < 4; ++h) {
        float a = enc_b[h];
        #pragma unroll
        for (int c = 0; c < 4; ++c) a += x_lds[c][l]*enc_W[c*4 + h];
        u[h] = a;
    }
    __syncthreads();

    for (int i = 0; i < NBLK; ++i) {
        float mu = 0.25f*(u[0]+u[1]+u[2]+u[3]);
        float var = 0.f;
        #pragma unroll
        for (int h = 0; h < 4; ++h) { float d = u[h]-mu; var += d*d; }
        var *= 0.25f;
        float rs = rsqrtf(var + 1e-5f);
        float z[4];
        #pragma unroll
        for (int h = 0; h < 4; ++h)
            z[h] = (u[h]-mu)*rs*ln_s[i*4 + h] + ln_b[i*4 + h];
        *(float4*)&z_lds[l][0] = make_float4(z[0], z[1], z[2], z[3]);
        __syncthreads();

        float y0 = 0.f, y1 = 0.f, y2 = 0.f, y3 = 0.f;
        const int mlim = l | 63;
        #pragma unroll 4
        for (int m = 0; m <= mlim; ++m) {
            float4 kk = *(const float4*)&Kl[i][m][0];
            int p = (l - m) & 255;
            float4 zz = *(const float4*)&z_lds[p][0];
            if (m <= l) {
                y0 += kk.x*zz.x; y1 += kk.y*zz.y;
                y2 += kk.z*zz.z; y3 += kk.w*zz.w;
            }
        }
        float y[4] = {y0, y1, y2, y3};
        #pragma unroll
        for (int h = 0; h < 4; ++h) {
            float v = y[h] + Dp[i*4 + h]*z[h];
            float inner = 0.7978845608028654f*(v + 0.044715f*v*v*v);
            y[h] = 0.5f*v*(1.0f + tanhf(inner));
        }
        #pragma unroll
        for (int k = 0; k < 4; ++k) {
            float a = out_b[i*4 + k];
            #pragma unroll
            for (int h = 0; h < 4; ++h) a += y[h]*out_W[(i*4 + h)*4 + k];
            u[k] += a;
        }
        __syncthreads();
    }

    #pragma unroll
    for (int h = 0; h < 4; ++h) {
        float a = dec_b[h];
        #pragma unroll
        for (int k = 0; k < 4; ++k) a += u[k]*dec_W[k*4 + h];
        s4_lds[l][h] = a;
    }
    __syncthreads();

    float* cmb = combined + b*1856;
    if (l < 64) {
        int h = l >> 4, kk = l & 15;
        float a = 0.f;
        #pragma unroll
        for (int j = 0; j < 16; ++j) a += s4_lds[kk*16 + j][h];
        cmb[l] = a*(1.0f/16.0f);
    }
    for (int e = l; e < 1792; e += 256) {
        int c = e/448, jj = e%448;
        float v;
        if (jj < 64) {
            v = 0.25f*(x_lds[c][4*jj] + x_lds[c][4*jj+1] +
                       x_lds[c][4*jj+2] + x_lds[c][4*jj+3]);
        } else if (jj < 192) {
            int q = jj - 64;
            v = 0.5f*(x_lds[c][2*q] + x_lds[c][2*q+1]);
        } else {
            v = x_lds[c][jj - 192];
        }
        cmb[64 + e] = v;
    }
}

// ---------------------------------------------------------------------------
// Kernel 2/4: partial GEMM, M=64 fixed, k4-vectorized inner loop.
// Block = [KCH k-chunk] x [64 j-tile]; parts[ks][64][NCOLS].
// ---------------------------------------------------------------------------
template<int NCOLS, int ASTRIDE, int KCH>
__global__ __launch_bounds__(256) void mlp_part(
    const float* __restrict__ A, const float* __restrict__ W,
    float* __restrict__ parts)
{
    constexpr int APAD = KCH + 4;
    __shared__ float At[64][APAD];
    __shared__ float Wl[KCH][64];
    const int ks = blockIdx.x, k0 = ks*KCH;
    const int j0 = blockIdx.y*64;
    const int t  = threadIdx.x;

    {
        constexpr int AF4 = 64*KCH/4;
        constexpr int RF4 = KCH/4;
        #pragma unroll
        for (int f = t; f < AF4; f += 256) {
            const int row = f / RF4, c4 = f % RF4;
            *(float4*)&At[row][c4*4] =
                *(const float4*)(A + (size_t)row*ASTRIDE + k0 + c4*4);
        }
        constexpr int WF4 = KCH*16;
        #pragma unroll
        for (int f = t; f < WF4; f += 256) {
            const int row = f >> 4, c4 = f & 15;
            *(float4*)&Wl[row][c4*4] =
                *(const float4*)(W + (size_t)(k0 + row)*NCOLS + j0 + c4*4);
        }
    }
    __syncthreads();

    const int ji = t & 15, br = (t >> 4)*4;
    float4 acc0={0,0,0,0}, acc1={0,0,0,0}, acc2={0,0,0,0}, acc3={0,0,0,0};
    #pragma unroll 4
    for (int k4 = 0; k4 < KCH; k4 += 4) {
        float4 w0 = *(float4*)&Wl[k4+0][ji*4];
        float4 w1 = *(float4*)&Wl[k4+1][ji*4];
        float4 w2 = *(float4*)&Wl[k4+2][ji*4];
        float4 w3 = *(float4*)&Wl[k4+3][ji*4];
        float4 a0 = *(float4*)&At[br+0][k4];
        float4 a1 = *(float4*)&At[br+1][k4];
        float4 a2 = *(float4*)&At[br+2][k4];
        float4 a3 = *(float4*)&At[br+3][k4];
        ACCROW(acc0, a0) ACCROW(acc1, a1) ACCROW(acc2, a2) ACCROW(acc3, a3)
    }
    float* pbase = parts + (size_t)(ks*64 + br)*NCOLS + j0 + ji*4;
    *(float4*)(pbase)           = acc0;
    *(float4*)(pbase + NCOLS)   = acc1;
    *(float4*)(pbase + 2*NCOLS) = acc2;
    *(float4*)(pbase + 3*NCOLS) = acc3;
}

// ---------------------------------------------------------------------------
// Kernel 3: sum partials + bias, LayerNorm + ReLU -> h1.  grid=64.
// ---------------------------------------------------------------------------
template<int N>
__global__ __launch_bounds__(256) void reduce_ln_relu(
    const float* __restrict__ parts, const float* __restrict__ bias,
    const float* __restrict__ g, const float* __restrict__ be,
    float* __restrict__ out, int KS)
{
    constexpr int NV = N/1024;
    const int b = blockIdx.x, t = threadIdx.x;
    float4 acc[NV];
    #pragma unroll
    for (int v = 0; v < NV; ++v)
        acc[v] = *(const float4*)(bias + v*1024 + t*4);
    for (int ks = 0; ks < KS; ++ks) {
        const float* p = parts + (size_t)(ks*64 + b)*N;
        #pragma unroll
        for (int v = 0; v < NV; ++v) {
            float4 q = *(const float4*)(p + v*1024 + t*4);
            acc[v].x += q.x; acc[v].y += q.y; acc[v].z += q.z; acc[v].w += q.w;
        }
    }
    float s = 0.f, s2 = 0.f;
    #pragma unroll
    for (int v = 0; v < NV; ++v) {
        s  += acc[v].x + acc[v].y + acc[v].z + acc[v].w;
        s2 += acc[v].x*acc[v].x + acc[v].y*acc[v].y +
              acc[v].z*acc[v].z + acc[v].w*acc[v].w;
    }
    #pragma unroll
    for (int off = 32; off > 0; off >>= 1) {
        s  += __shfl_down(s,  off);
        s2 += __shfl_down(s2, off);
    }
    __shared__ float red[2][4];
    const int w = t >> 6;
    if ((t & 63) == 0) { red[0][w] = s; red[1][w] = s2; }
    __syncthreads();
    float ts  = red[0][0] + red[0][1] + red[0][2] + red[0][3];
    float ts2 = red[1][0] + red[1][1] + red[1][2] + red[1][3];
    const float inv_n = 1.0f/(float)N;
    float mu  = ts*inv_n;
    float var = ts2*inv_n - mu*mu;
    float rs  = rsqrtf(var + 1e-5f);
    #pragma unroll
    for (int v = 0; v < NV; ++v) {
        const int j = v*1024 + t*4;
        float4 gv  = *(const float4*)(g + j);
        float4 bev = *(const float4*)(be + j);
        float4 o;
        o.x = fmaxf((acc[v].x - mu)*rs*gv.x + bev.x, 0.f);
        o.y = fmaxf((acc[v].y - mu)*rs*gv.y + bev.y, 0.f);
        o.z = fmaxf((acc[v].z - mu)*rs*gv.z + bev.z, 0.f);
        o.w = fmaxf((acc[v].w - mu)*rs*gv.w + bev.w, 0.f);
        *(float4*)(out + (size_t)b*N + j) = o;
    }
}

// ---------------------------------------------------------------------------
// Kernel 5 (fused): red2 + LN + ReLU + final matmul -> out [64,512,4096].
// grid = 512 blocks; block rg owns b = rg>>3, s in [(rg&7)*64, +64).
// Phase 1: recompute row-b LN stats + this block's 512 h-values from parts2.
// Phase 2: lane r holds h[r][0..8) in VGPRs; readlane broadcasts; f4 stores.
// ---------------------------------------------------------------------------
__global__ __launch_bounds__(256) void final_fused(
    const float* __restrict__ parts2, const float* __restrict__ b2,
    const float* __restrict__ g2, const float* __restrict__ be2,
    const float* __restrict__ W3, const float* __restrict__ b3,
    float* __restrict__ out)
{
    const int rg = blockIdx.x;      // 0..511
    const int t  = threadIdx.x;
    const int b  = rg >> 3;
    const int cbase = (rg & 7)*512; // h-row column base for this block
    __shared__ float hrow_l[512];
    __shared__ float red[2][4];

    // ---- Phase 1: thread t owns cols [t*16, t*16+16) of h2pre row b ----
    float4 vals[4];
    float s = 0.f, s2 = 0.f;
    #pragma unroll
    for (int v = 0; v < 4; ++v) {
        const int j = t*16 + v*4;
        float4 acc = *(const float4*)(b2 + j);
        #pragma unroll
        for (int ks = 0; ks < 8; ++ks) {
            float4 q = *(const float4*)(parts2 + (size_t)(ks*64 + b)*4096 + j);
            acc.x += q.x; acc.y += q.y; acc.z += q.z; acc.w += q.w;
        }
        vals[v] = acc;
        s  += acc.x + acc.y + acc.z + acc.w;
        s2 += acc.x*acc.x + acc.y*acc.y + acc.z*acc.z + acc.w*acc.w;
    }
    #pragma unroll
    for (int off = 32; off > 0; off >>= 1) {
        s  += __shfl_down(s,  off);
        s2 += __shfl_down(s2, off);
    }
    const int w = t >> 6;
    if ((t & 63) == 0) { red[0][w] = s; red[1][w] = s2; }
    __syncthreads();
    float ts  = red[0][0] + red[0][1] + red[0][2] + red[0][3];
    float ts2 = red[1][0] + red[1][1] + red[1][2] + red[1][3];
    float mu  = ts*(1.0f/4096.0f);
    float var = ts2*(1.0f/4096.0f) - mu*mu;
    float rs  = rsqrtf(var + 1e-5f);
    // writers: threads owning cols [cbase, cbase+512)
    if (t >= (rg & 7)*32 && t < (rg & 7)*32 + 32) {
        #pragma unroll
        for (int v = 0; v < 4; ++v) {
            const int j = t*16 + v*4;
            float4 gv  = *(const float4*)(g2 + j);
            float4 bev = *(const float4*)(be2 + j);
            float4 o;
            o.x = fmaxf((vals[v].x - mu)*rs*gv.x + bev.x, 0.f);
            o.y = fmaxf((vals[v].y - mu)*rs*gv.y + bev.y, 0.f);
            o.z = fmaxf((vals[v].z - mu)*rs*gv.z + bev.z, 0.f);
            o.w = fmaxf((vals[v].w - mu)*rs*gv.w + bev.w, 0.f);
            *(float4*)&hrow_l[j - cbase] = o;
        }
    }
    __syncthreads();

    // ---- Phase 2: lane L of each wave holds h[L][0..8) in 8 VGPRs ----
    const int lane = t & 63;
    float hreg[8];
    {
        float4 ha = *(float4*)&hrow_l[lane*8];
        float4 hb = *(float4*)&hrow_l[lane*8 + 4];
        hreg[0]=ha.x; hreg[1]=ha.y; hreg[2]=ha.z; hreg[3]=ha.w;
        hreg[4]=hb.x; hreg[5]=hb.y; hreg[6]=hb.z; hreg[7]=hb.w;
    }
    const int bs0 = rg*64;   // = b*512 + (rg&7)*64
    for (int js = 0; js < 4; ++js) {
        const int j = js*1024 + t*4;
        float4 wv[8];
        #pragma unroll
        for (int k = 0; k < 8; ++k)
            wv[k] = *(const float4*)(W3 + k*4096 + j);
        const float4 bv = *(const float4*)(b3 + j);
        float* __restrict__ obase = out + (size_t)bs0*4096 + j;
        #pragma unroll 4
        for (int r = 0; r < 64; ++r) {
            float4 acc = bv;
            #pragma unroll
            for (int k = 0; k < 8; ++k) {
                const float hv = lane_bcast(hreg[k], r);
                acc.x += hv*wv[k].x; acc.y += hv*wv[k].y;
                acc.z += hv*wv[k].z; acc.w += hv*wv[k].w;
            }
            *(float4*)(obase + (size_t)r*4096) = acc;
        }
    }
}

// ---------------------------------------------------------------------------
extern "C" void kernel_launch(void* const* d_in, const int* in_sizes, int n_in,
                              void* d_out, int out_size, void* d_ws, size_t ws_size,
                              hipStream_t stream) {
    const float* x      = (const float*)d_in[0];
    const float* enc_W  = (const float*)d_in[1];
    const float* enc_b  = (const float*)d_in[2];
    const float* ln_s   = (const float*)d_in[3];
    const float* ln_b   = (const float*)d_in[4];
    const float* log_dt = (const float*)d_in[5];
    const float* A_re   = (const float*)d_in[6];
    const float* A_im   = (const float*)d_in[7];
    const float* C_re   = (const float*)d_in[8];
    const float* C_im   = (const float*)d_in[9];
    const float* Dp     = (const float*)d_in[10];
    const float* out_W  = (const float*)d_in[11];
    const float* out_b  = (const float*)d_in[12];
    const float* dec_W  = (const float*)d_in[13];
    const float* dec_b  = (const float*)d_in[14];
    const float* W1     = (const float*)d_in[15];
    const float* b1     = (const float*)d_in[16];
    const float* g1     = (const float*)d_in[17];
    const float* be1    = (const float*)d_in[18];
    const float* W2     = (const float*)d_in[19];
    const float* b2     = (const float*)d_in[20];
    const float* g2     = (const float*)d_in[21];
    const float* be2    = (const float*)d_in[22];
    const float* W3     = (const float*)d_in[23];
    const float* b3     = (const float*)d_in[24];
    float* out = (float*)d_out;

    float* ws = (float*)d_ws;
    float* combined = ws;                        // 64*1856
    float* parts1   = combined + 64*1856;        // 29*64*1024
    float* h1       = parts1 + 29*64*1024;       // 64*1024
    float* parts2   = h1 + 64*1024;              // 8*64*4096

    s4front<<<64, 256, 0, stream>>>(x, enc_W, enc_b, ln_s, ln_b, log_dt,
                                    A_re, A_im, C_re, C_im, Dp,
                                    out_W, out_b, dec_W, dec_b, combined);
    mlp_part<1024,1856,64><<<dim3(29,16), 256, 0, stream>>>(combined, W1, parts1);
    reduce_ln_relu<1024><<<64, 256, 0, stream>>>(parts1, b1, g1, be1, h1, 29);
    mlp_part<4096,1024,128><<<dim3(8,64), 256, 0, stream>>>(h1, W2, parts2);
    final_fused<<<512, 256, 0, stream>>>(parts2, b2, g2, be2, W3, b3, out);
}

// Round 10
// 189.488 us; speedup vs baseline: 3.4313x; 1.1009x over previous
//
#include <hip/hip_runtime.h>
#include <hip/hip_bf16.h>
#include <math.h>

// Problem constants
#define BDEF 64
#define LSEQ 256
#define HD   4
#define NST  4
#define NBLK 2

typedef float nfloat4 __attribute__((ext_vector_type(4)));  // native vec for nt ops

__device__ inline void nt_store4(const float4 v, float* p) {
    nfloat4 nv = {v.x, v.y, v.z, v.w};
    __builtin_nontemporal_store(nv, (nfloat4*)p);
}

// acc_row += a.{x,y,z,w} * w{0,1,2,3} (component-wise over 4 j)
#define ACCROW(accv, av)                                        \
    accv.x += av.x*w0.x + av.y*w1.x + av.z*w2.x + av.w*w3.x;    \
    accv.y += av.x*w0.y + av.y*w1.y + av.z*w2.y + av.w*w3.y;    \
    accv.z += av.x*w0.z + av.y*w1.z + av.z*w2.z + av.w*w3.z;    \
    accv.w += av.x*w0.w + av.y*w1.w + av.z*w2.w + av.w*w3.w;

// ---------------------------------------------------------------------------
// Kernel 1: K-comp + encoder + 2x S4D block + decoder + pooling
//           -> combined [64,1856].  grid=64 (one block per batch), block=256.
// ---------------------------------------------------------------------------
__global__ __launch_bounds__(256) void s4front(
    const float* __restrict__ x, const float* __restrict__ enc_W,
    const float* __restrict__ enc_b, const float* __restrict__ ln_s,
    const float* __restrict__ ln_b, const float* __restrict__ log_dt,
    const float* __restrict__ A_re, const float* __restrict__ A_im,
    const float* __restrict__ C_re, const float* __restrict__ C_im,
    const float* __restrict__ Dp, const float* __restrict__ out_W,
    const float* __restrict__ out_b, const float* __restrict__ dec_W,
    const float* __restrict__ dec_b, float* __restrict__ combined)
{
    const int b = blockIdx.x;
    const int l = threadIdx.x;
    __shared__ float Kl[NBLK][LSEQ][4];   // conv kernels, 8 KB
    __shared__ float x_lds[4][256];       // raw input row
    __shared__ float z_lds[256][4];       // pre-conv activations ([l][h], b128)
    __shared__ float s4_lds[256][4];      // decoder output for pooling

    // ---- compute SSM kernels K[i][m][h] (thread m = l) ----
    {
        const float t = (float)l;
        for (int i = 0; i < NBLK; ++i) {
            #pragma unroll
            for (int h = 0; h < HD; ++h) {
                float dt = expf(log_dt[i*HD + h]);
                float acc = 0.f;
                #pragma unroll
                for (int n = 0; n < NST; ++n) {
                    const int idx = (i*HD + h)*NST + n;
                    float ar = -expf(A_re[idx]);     // Re(A)
                    float ai = A_im[idx];            // Im(A)
                    float dr = ar*dt, di = ai*dt;    // dtA
                    float er  = expf(dr);            // Bd = (exp(dtA)-1)/A
                    float e1r = er*cosf(di) - 1.0f;
                    float e1i = er*sinf(di);
                    float inv = 1.0f/(ar*ar + ai*ai);
                    float bdr = (e1r*ar + e1i*ai)*inv;
                    float bdi = (e1i*ar - e1r*ai)*inv;
                    float cr = C_re[idx], ci = C_im[idx];
                    float cbr = cr*bdr - ci*bdi;     // C*Bd
                    float cbi = cr*bdi + ci*bdr;
                    float em = expf(dr*t);           // vand = exp(dtA*t)
                    float vr = em*cosf(di*t);
                    float vi = em*sinf(di*t);
                    acc += cbr*vr - cbi*vi;
                }
                Kl[i][l][h] = 2.0f*acc;
            }
        }
    }

    #pragma unroll
    for (int c = 0; c < 4; ++c)
        x_lds[c][l] = x[(b*4 + c)*256 + l];

    // encoder: u[h] = sum_c x[c,l]*enc_W[c,h] + enc_b[h]
    float u[4];
    #pragma unroll
    for (int h = 0; h < 4; ++h) {
        float a = enc_b[h];
        #pragma unroll
        for (int c = 0; c < 4; ++c) a += x_lds[c][l]*enc_W[c*4 + h];
        u[h] = a;
    }
    __syncthreads();

    for (int i = 0; i < NBLK; ++i) {
        // prenorm LN over H=4
        float mu = 0.25f*(u[0]+u[1]+u[2]+u[3]);
        float var = 0.f;
        #pragma unroll
        for (int h = 0; h < 4; ++h) { float d = u[h]-mu; var += d*d; }
        var *= 0.25f;
        float rs = rsqrtf(var + 1e-5f);
        float z[4];
        #pragma unroll
        for (int h = 0; h < 4; ++h)
            z[h] = (u[h]-mu)*rs*ln_s[i*4 + h] + ln_b[i*4 + h];
        *(float4*)&z_lds[l][0] = make_float4(z[0], z[1], z[2], z[3]);
        __syncthreads();

        // causal convolution: y[h] = sum_{m<=l} K[i][m][h]*z[l-m][h]
        float y0 = 0.f, y1 = 0.f, y2 = 0.f, y3 = 0.f;
        const int mlim = l | 63;   // wave-uniform upper bound
        #pragma unroll 4
        for (int m = 0; m <= mlim; ++m) {
            float4 kk = *(const float4*)&Kl[i][m][0];  // uniform -> broadcast
            int p = (l - m) & 255;                     // safe wrap (masked tail)
            float4 zz = *(const float4*)&z_lds[p][0];
            if (m <= l) {
                y0 += kk.x*zz.x; y1 += kk.y*zz.y;
                y2 += kk.z*zz.z; y3 += kk.w*zz.w;
            }
        }
        float y[4] = {y0, y1, y2, y3};
        // skip + gelu (tanh approximation, jax.nn.gelu default)
        #pragma unroll
        for (int h = 0; h < 4; ++h) {
            float v = y[h] + Dp[i*4 + h]*z[h];
            float inner = 0.7978845608028654f*(v + 0.044715f*v*v*v);
            y[h] = 0.5f*v*(1.0f + tanhf(inner));
        }
        // output projection over h + residual
        #pragma unroll
        for (int k = 0; k < 4; ++k) {
            float a = out_b[i*4 + k];
            #pragma unroll
            for (int h = 0; h < 4; ++h) a += y[h]*out_W[(i*4 + h)*4 + k];
            u[k] += a;
        }
        __syncthreads();   // protect z_lds before next iteration overwrite
    }

    // decoder
    #pragma unroll
    for (int h = 0; h < 4; ++h) {
        float a = dec_b[h];
        #pragma unroll
        for (int k = 0; k < 4; ++k) a += u[k]*dec_W[k*4 + h];
        s4_lds[l][h] = a;
    }
    __syncthreads();

    float* cmb = combined + b*1856;
    // z16: [4,16] pooled (window 16), flattened h*16+k
    if (l < 64) {
        int h = l >> 4, kk = l & 15;
        float a = 0.f;
        #pragma unroll
        for (int j = 0; j < 16; ++j) a += s4_lds[kk*16 + j][h];
        cmb[l] = a*(1.0f/16.0f);
    }
    // fpp: [4,448] = concat(pool64(win4), pool128(win2), raw256), offset 64
    for (int e = l; e < 1792; e += 256) {
        int c = e/448, jj = e%448;
        float v;
        if (jj < 64) {
            v = 0.25f*(x_lds[c][4*jj] + x_lds[c][4*jj+1] +
                       x_lds[c][4*jj+2] + x_lds[c][4*jj+3]);
        } else if (jj < 192) {
            int q = jj - 64;
            v = 0.5f*(x_lds[c][2*q] + x_lds[c][2*q+1]);
        } else {
            v = x_lds[c][jj - 192];
        }
        cmb[64 + e] = v;
    }
}

// ---------------------------------------------------------------------------
// Kernel 2/4: partial GEMM, M=64 fixed, k4-vectorized ACCROW inner loop
// (all-b128 LDS reads). Block = [KCH k-chunk] x [64 j-tile];
// parts[ks][64][NCOLS]. grid = (K/KCH, NCOLS/64), block 256.
// ---------------------------------------------------------------------------
template<int NCOLS, int ASTRIDE, int KCH>
__global__ __launch_bounds__(256) void mlp_part(
    const float* __restrict__ A, const float* __restrict__ W,
    float* __restrict__ parts)
{
    constexpr int APAD = KCH + 4;
    __shared__ float At[64][APAD];     // A chunk, [b][k], padded
    __shared__ float Wl[KCH][64];      // W tile [k][j]
    const int ks = blockIdx.x, k0 = ks*KCH;
    const int j0 = blockIdx.y*64;
    const int t  = threadIdx.x;

    {
        constexpr int AF4 = 64*KCH/4;
        constexpr int RF4 = KCH/4;
        #pragma unroll
        for (int f = t; f < AF4; f += 256) {
            const int row = f / RF4, c4 = f % RF4;
            *(float4*)&At[row][c4*4] =
                *(const float4*)(A + (size_t)row*ASTRIDE + k0 + c4*4);
        }
        constexpr int WF4 = KCH*16;
        #pragma unroll
        for (int f = t; f < WF4; f += 256) {
            const int row = f >> 4, c4 = f & 15;
            *(float4*)&Wl[row][c4*4] =
                *(const float4*)(W + (size_t)(k0 + row)*NCOLS + j0 + c4*4);
        }
    }
    __syncthreads();

    const int ji = t & 15, br = (t >> 4)*4;
    float4 acc0={0,0,0,0}, acc1={0,0,0,0}, acc2={0,0,0,0}, acc3={0,0,0,0};
    #pragma unroll 4
    for (int k4 = 0; k4 < KCH; k4 += 4) {
        float4 w0 = *(float4*)&Wl[k4+0][ji*4];
        float4 w1 = *(float4*)&Wl[k4+1][ji*4];
        float4 w2 = *(float4*)&Wl[k4+2][ji*4];
        float4 w3 = *(float4*)&Wl[k4+3][ji*4];
        float4 a0 = *(float4*)&At[br+0][k4];
        float4 a1 = *(float4*)&At[br+1][k4];
        float4 a2 = *(float4*)&At[br+2][k4];
        float4 a3 = *(float4*)&At[br+3][k4];
        ACCROW(acc0, a0) ACCROW(acc1, a1) ACCROW(acc2, a2) ACCROW(acc3, a3)
    }
    float* pbase = parts + (size_t)(ks*64 + br)*NCOLS + j0 + ji*4;
    *(float4*)(pbase)           = acc0;
    *(float4*)(pbase + NCOLS)   = acc1;
    *(float4*)(pbase + 2*NCOLS) = acc2;
    *(float4*)(pbase + 3*NCOLS) = acc3;
}

// ---------------------------------------------------------------------------
// Kernel 3/5: sum partials + bias, then LayerNorm + ReLU.  grid=64 (per b).
// ---------------------------------------------------------------------------
template<int N>
__global__ __launch_bounds__(256) void reduce_ln_relu(
    const float* __restrict__ parts, const float* __restrict__ bias,
    const float* __restrict__ g, const float* __restrict__ be,
    float* __restrict__ out, int KS)
{
    constexpr int NV = N/1024;      // float4 per thread
    const int b = blockIdx.x, t = threadIdx.x;
    float4 acc[NV];
    #pragma unroll
    for (int v = 0; v < NV; ++v)
        acc[v] = *(const float4*)(bias + v*1024 + t*4);
    for (int ks = 0; ks < KS; ++ks) {
        const float* p = parts + (size_t)(ks*64 + b)*N;
        #pragma unroll
        for (int v = 0; v < NV; ++v) {
            float4 q = *(const float4*)(p + v*1024 + t*4);
            acc[v].x += q.x; acc[v].y += q.y; acc[v].z += q.z; acc[v].w += q.w;
        }
    }
    float s = 0.f, s2 = 0.f;
    #pragma unroll
    for (int v = 0; v < NV; ++v) {
        s  += acc[v].x + acc[v].y + acc[v].z + acc[v].w;
        s2 += acc[v].x*acc[v].x + acc[v].y*acc[v].y +
              acc[v].z*acc[v].z + acc[v].w*acc[v].w;
    }
    #pragma unroll
    for (int off = 32; off > 0; off >>= 1) {
        s  += __shfl_down(s,  off);
        s2 += __shfl_down(s2, off);
    }
    __shared__ float red[2][4];
    const int w = t >> 6;
    if ((t & 63) == 0) { red[0][w] = s; red[1][w] = s2; }
    __syncthreads();
    float ts  = red[0][0] + red[0][1] + red[0][2] + red[0][3];
    float ts2 = red[1][0] + red[1][1] + red[1][2] + red[1][3];
    const float inv_n = 1.0f/(float)N;
    float mu  = ts*inv_n;
    float var = ts2*inv_n - mu*mu;
    float rs  = rsqrtf(var + 1e-5f);
    #pragma unroll
    for (int v = 0; v < NV; ++v) {
        const int j = v*1024 + t*4;
        float4 gv  = *(const float4*)(g + j);
        float4 bev = *(const float4*)(be + j);
        float4 o;
        o.x = fmaxf((acc[v].x - mu)*rs*gv.x + bev.x, 0.f);
        o.y = fmaxf((acc[v].y - mu)*rs*gv.y + bev.y, 0.f);
        o.z = fmaxf((acc[v].z - mu)*rs*gv.z + bev.z, 0.f);
        o.w = fmaxf((acc[v].w - mu)*rs*gv.w + bev.w, 0.f);
        *(float4*)(out + (size_t)b*N + j) = o;
    }
}

// ---------------------------------------------------------------------------
// Kernel 6: out[b,s,:] = h2[b, s*8 .. s*8+7] @ W3 + b3 -> [64,512,4096] f32
// grid = (512 row-groups of 64 rows, 4 j-slices of 1024), block 256.
// h2 reads wave-uniform -> s_load (K$); W3 in registers; NT float4 stores.
// ---------------------------------------------------------------------------
#define ROWS_D 64
__global__ __launch_bounds__(256) void final_mm(
    const float* __restrict__ h2, const float* __restrict__ W3,
    const float* __restrict__ b3, float* __restrict__ out)
{
    const int rg = blockIdx.x;
    const int js = blockIdx.y;
    const int t  = threadIdx.x;
    const int bs0 = rg*ROWS_D;
    const int j = js*1024 + t*4;
    float4 w[8];
    #pragma unroll
    for (int k = 0; k < 8; ++k) w[k] = *(const float4*)(W3 + k*4096 + j);
    const float4 bv = *(const float4*)(b3 + j);
    const float* __restrict__ hrow = h2 + (size_t)bs0*8;
    float* __restrict__ obase = out + (size_t)bs0*4096 + j;
    #pragma unroll 4
    for (int r = 0; r < ROWS_D; ++r) {
        float4 acc = bv;
        #pragma unroll
        for (int k = 0; k < 8; ++k) {
            const float hv = hrow[r*8 + k];   // wave-uniform -> s_load (K$)
            acc.x += hv*w[k].x; acc.y += hv*w[k].y;
            acc.z += hv*w[k].z; acc.w += hv*w[k].w;
        }
        nt_store4(acc, obase + (size_t)r*4096);
    }
}

// ---------------------------------------------------------------------------
extern "C" void kernel_launch(void* const* d_in, const int* in_sizes, int n_in,
                              void* d_out, int out_size, void* d_ws, size_t ws_size,
                              hipStream_t stream) {
    const float* x      = (const float*)d_in[0];
    const float* enc_W  = (const float*)d_in[1];
    const float* enc_b  = (const float*)d_in[2];
    const float* ln_s   = (const float*)d_in[3];
    const float* ln_b   = (const float*)d_in[4];
    const float* log_dt = (const float*)d_in[5];
    const float* A_re   = (const float*)d_in[6];
    const float* A_im   = (const float*)d_in[7];
    const float* C_re   = (const float*)d_in[8];
    const float* C_im   = (const float*)d_in[9];
    const float* Dp     = (const float*)d_in[10];
    const float* out_W  = (const float*)d_in[11];
    const float* out_b  = (const float*)d_in[12];
    const float* dec_W  = (const float*)d_in[13];
    const float* dec_b  = (const float*)d_in[14];
    const float* W1     = (const float*)d_in[15];
    const float* b1     = (const float*)d_in[16];
    const float* g1     = (const float*)d_in[17];
    const float* be1    = (const float*)d_in[18];
    const float* W2     = (const float*)d_in[19];
    const float* b2     = (const float*)d_in[20];
    const float* g2     = (const float*)d_in[21];
    const float* be2    = (const float*)d_in[22];
    const float* W3     = (const float*)d_in[23];
    const float* b3     = (const float*)d_in[24];
    float* out = (float*)d_out;

    float* ws = (float*)d_ws;
    float* combined = ws;                        // 64*1856
    float* parts1   = combined + 64*1856;        // 29*64*1024
    float* h1       = parts1 + 29*64*1024;       // 64*1024
    float* parts2   = h1 + 64*1024;              // 8*64*4096
    float* h2       = parts2 + 8*64*4096;        // 64*4096

    s4front<<<64, 256, 0, stream>>>(x, enc_W, enc_b, ln_s, ln_b, log_dt,
                                    A_re, A_im, C_re, C_im, Dp,
                                    out_W, out_b, dec_W, dec_b, combined);
    mlp_part<1024,1856,64><<<dim3(29,16), 256, 0, stream>>>(combined, W1, parts1);
    reduce_ln_relu<1024><<<64, 256, 0, stream>>>(parts1, b1, g1, be1, h1, 29);
    mlp_part<4096,1024,128><<<dim3(8,64), 256, 0, stream>>>(h1, W2, parts2);
    reduce_ln_relu<4096><<<64, 256, 0, stream>>>(parts2, b2, g2, be2, h2, 8);
    final_mm<<<dim3(512,4), 256, 0, stream>>>(h2, W3, b3, out);
}

// Round 11
// 166.588 us; speedup vs baseline: 3.9030x; 1.1375x over previous
//
#include <hip/hip_runtime.h>
#include <hip/hip_bf16.h>
#include <math.h>

// Problem constants
#define BDEF 64
#define LSEQ 256
#define HD   4
#define NST  4
#define NBLK 2
#define SPLIT 4   // conv m-split factor in s4front

typedef float nfloat4 __attribute__((ext_vector_type(4)));  // native vec for nt ops

__device__ inline void nt_store4(const float4 v, float* p) {
    nfloat4 nv = {v.x, v.y, v.z, v.w};
    __builtin_nontemporal_store(nv, (nfloat4*)p);
}

// acc_row += a.{x,y,z,w} * w{0,1,2,3} (component-wise over 4 j)
#define ACCROW(accv, av)                                        \
    accv.x += av.x*w0.x + av.y*w1.x + av.z*w2.x + av.w*w3.x;    \
    accv.y += av.x*w0.y + av.y*w1.y + av.z*w2.y + av.w*w3.y;    \
    accv.z += av.x*w0.z + av.y*w1.z + av.z*w2.z + av.w*w3.z;    \
    accv.w += av.x*w0.w + av.y*w1.w + av.z*w2.w + av.w*w3.w;

// ---------------------------------------------------------------------------
// Kernel 1: K-comp + encoder + 2x S4D block + decoder + pooling
//           -> combined [64,1856].
// grid=64 (one block per batch), block=1024 (4 m-split parts x 256 l).
// The serial conv chain is split 4-way over m; partials combined in LDS.
// ---------------------------------------------------------------------------
__global__ __launch_bounds__(1024) void s4front(
    const float* __restrict__ x, const float* __restrict__ enc_W,
    const float* __restrict__ enc_b, const float* __restrict__ ln_s,
    const float* __restrict__ ln_b, const float* __restrict__ log_dt,
    const float* __restrict__ A_re, const float* __restrict__ A_im,
    const float* __restrict__ C_re, const float* __restrict__ C_im,
    const float* __restrict__ Dp, const float* __restrict__ out_W,
    const float* __restrict__ out_b, const float* __restrict__ dec_W,
    const float* __restrict__ dec_b, float* __restrict__ combined)
{
    const int b    = blockIdx.x;
    const int t    = threadIdx.x;
    const int l    = t & 255;
    const int part = t >> 8;            // 0..3, wave-uniform
    __shared__ float Kl[NBLK][LSEQ][4];     // conv kernels, 8 KB
    __shared__ float x_lds[4][256];         // raw input row, 4 KB
    __shared__ float z_lds[256][4];         // pre-conv activations, 4 KB
    __shared__ float s4_lds[256][4];        // decoder output, 4 KB
    __shared__ float yp[SPLIT][256][4];     // conv partials, 16 KB

    // ---- SSM kernels K[i][m][h]: threads t<512, i=part, m=l ----
    if (t < 512) {
        const int i = part;             // 0 or 1
        const float tt = (float)l;
        #pragma unroll
        for (int h = 0; h < HD; ++h) {
            float dt = expf(log_dt[i*HD + h]);
            float acc = 0.f;
            #pragma unroll
            for (int n = 0; n < NST; ++n) {
                const int idx = (i*HD + h)*NST + n;
                float ar = -expf(A_re[idx]);     // Re(A)
                float ai = A_im[idx];            // Im(A)
                float dr = ar*dt, di = ai*dt;    // dtA
                float er  = expf(dr);            // Bd = (exp(dtA)-1)/A
                float e1r = er*cosf(di) - 1.0f;
                float e1i = er*sinf(di);
                float inv = 1.0f/(ar*ar + ai*ai);
                float bdr = (e1r*ar + e1i*ai)*inv;
                float bdi = (e1i*ar - e1r*ai)*inv;
                float cr = C_re[idx], ci = C_im[idx];
                float cbr = cr*bdr - ci*bdi;     // C*Bd
                float cbi = cr*bdi + ci*bdr;
                float em = expf(dr*tt);          // vand = exp(dtA*t)
                float vr = em*cosf(di*tt);
                float vi = em*sinf(di*tt);
                acc += cbr*vr - cbi*vi;
            }
            Kl[i][l][h] = 2.0f*acc;
        }
    }

    if (part == 0) {
        #pragma unroll
        for (int c = 0; c < 4; ++c)
            x_lds[c][l] = x[(b*4 + c)*256 + l];
    }
    __syncthreads();

    // encoder (all parts duplicate; register-only state)
    float u[4];
    #pragma unroll
    for (int h = 0; h < 4; ++h) {
        float a = enc_b[h];
        #pragma unroll
        for (int c = 0; c < 4; ++c) a += x_lds[c][l]*enc_W[c*4 + h];
        u[h] = a;
    }

    const int mlim = l | 63;            // wave-uniform conv bound
    const int m0   = part*64;           // wave-uniform part range start

    for (int i = 0; i < NBLK; ++i) {
        // prenorm LN over H=4 (all parts duplicate)
        float mu = 0.25f*(u[0]+u[1]+u[2]+u[3]);
        float var = 0.f;
        #pragma unroll
        for (int h = 0; h < 4; ++h) { float d = u[h]-mu; var += d*d; }
        var *= 0.25f;
        float rs = rsqrtf(var + 1e-5f);
        float z[4];
        #pragma unroll
        for (int h = 0; h < 4; ++h)
            z[h] = (u[h]-mu)*rs*ln_s[i*4 + h] + ln_b[i*4 + h];
        if (part == 0)
            *(float4*)&z_lds[l][0] = make_float4(z[0], z[1], z[2], z[3]);
        __syncthreads();   // A: z_lds visible to all parts

        // conv partial: m in [m0, min(m0+63, mlim)], mask m<=l
        float y0 = 0.f, y1 = 0.f, y2 = 0.f, y3 = 0.f;
        const int mhi = min(m0 + 63, mlim);
        #pragma unroll 4
        for (int m = m0; m <= mhi; ++m) {
            float4 kk = *(const float4*)&Kl[i][m][0];
            int p = (l - m) & 255;
            float4 zz = *(const float4*)&z_lds[p][0];
            if (m <= l) {
                y0 += kk.x*zz.x; y1 += kk.y*zz.y;
                y2 += kk.z*zz.z; y3 += kk.w*zz.w;
            }
        }
        *(float4*)&yp[part][l][0] = make_float4(y0, y1, y2, y3);
        __syncthreads();   // B: partials ready

        float4 p0 = *(const float4*)&yp[0][l][0];
        float4 p1 = *(const float4*)&yp[1][l][0];
        float4 p2 = *(const float4*)&yp[2][l][0];
        float4 p3 = *(const float4*)&yp[3][l][0];
        float y[4] = { p0.x+p1.x+p2.x+p3.x, p0.y+p1.y+p2.y+p3.y,
                       p0.z+p1.z+p2.z+p3.z, p0.w+p1.w+p2.w+p3.w };
        // skip + gelu (tanh approximation) — all parts duplicate
        #pragma unroll
        for (int h = 0; h < 4; ++h) {
            float v = y[h] + Dp[i*4 + h]*z[h];
            float inner = 0.7978845608028654f*(v + 0.044715f*v*v*v);
            y[h] = 0.5f*v*(1.0f + tanhf(inner));
        }
        // output projection + residual
        #pragma unroll
        for (int k = 0; k < 4; ++k) {
            float a = out_b[i*4 + k];
            #pragma unroll
            for (int h = 0; h < 4; ++h) a += y[h]*out_W[(i*4 + h)*4 + k];
            u[k] += a;
        }
        __syncthreads();   // C: yp/z_lds reads done before next-iter rewrite
    }

    // decoder (part 0 writes; all parts hold identical u)
    if (part == 0) {
        #pragma unroll
        for (int h = 0; h < 4; ++h) {
            float a = dec_b[h];
            #pragma unroll
            for (int k = 0; k < 4; ++k) a += u[k]*dec_W[k*4 + h];
            s4_lds[l][h] = a;
        }
    }
    __syncthreads();

    float* cmb = combined + b*1856;
    // z16: [4,16] pooled (window 16), flattened h*16+k
    if (t < 64) {
        int h = t >> 4, kk = t & 15;
        float a = 0.f;
        #pragma unroll
        for (int j = 0; j < 16; ++j) a += s4_lds[kk*16 + j][h];
        cmb[t] = a*(1.0f/16.0f);
    }
    // fpp: [4,448] = concat(pool64(win4), pool128(win2), raw256), offset 64
    for (int e = t; e < 1792; e += 1024) {
        int c = e/448, jj = e%448;
        float v;
        if (jj < 64) {
            v = 0.25f*(x_lds[c][4*jj] + x_lds[c][4*jj+1] +
                       x_lds[c][4*jj+2] + x_lds[c][4*jj+3]);
        } else if (jj < 192) {
            int q = jj - 64;
            v = 0.5f*(x_lds[c][2*q] + x_lds[c][2*q+1]);
        } else {
            v = x_lds[c][jj - 192];
        }
        cmb[64 + e] = v;
    }
}

// ---------------------------------------------------------------------------
// Kernel 2/4: partial GEMM, M=64 fixed, k4-vectorized ACCROW inner loop.
// Block = [KCH k-chunk] x [64 j-tile]; parts[ks][64][NCOLS].
// grid = (K/KCH, NCOLS/64), block 256. KCH=64 -> 33 KB LDS, 4 blocks/CU.
// ---------------------------------------------------------------------------
template<int NCOLS, int ASTRIDE, int KCH>
__global__ __launch_bounds__(256) void mlp_part(
    const float* __restrict__ A, const float* __restrict__ W,
    float* __restrict__ parts)
{
    constexpr int APAD = KCH + 4;
    __shared__ float At[64][APAD];     // A chunk, [b][k], padded
    __shared__ float Wl[KCH][64];      // W tile [k][j]
    const int ks = blockIdx.x, k0 = ks*KCH;
    const int j0 = blockIdx.y*64;
    const int t  = threadIdx.x;

    {
        constexpr int AF4 = 64*KCH/4;
        constexpr int RF4 = KCH/4;
        #pragma unroll
        for (int f = t; f < AF4; f += 256) {
            const int row = f / RF4, c4 = f % RF4;
            *(float4*)&At[row][c4*4] =
                *(const float4*)(A + (size_t)row*ASTRIDE + k0 + c4*4);
        }
        constexpr int WF4 = KCH*16;
        #pragma unroll
        for (int f = t; f < WF4; f += 256) {
            const int row = f >> 4, c4 = f & 15;
            *(float4*)&Wl[row][c4*4] =
                *(const float4*)(W + (size_t)(k0 + row)*NCOLS + j0 + c4*4);
        }
    }
    __syncthreads();

    const int ji = t & 15, br = (t >> 4)*4;
    float4 acc0={0,0,0,0}, acc1={0,0,0,0}, acc2={0,0,0,0}, acc3={0,0,0,0};
    #pragma unroll 4
    for (int k4 = 0; k4 < KCH; k4 += 4) {
        float4 w0 = *(float4*)&Wl[k4+0][ji*4];
        float4 w1 = *(float4*)&Wl[k4+1][ji*4];
        float4 w2 = *(float4*)&Wl[k4+2][ji*4];
        float4 w3 = *(float4*)&Wl[k4+3][ji*4];
        float4 a0 = *(float4*)&At[br+0][k4];
        float4 a1 = *(float4*)&At[br+1][k4];
        float4 a2 = *(float4*)&At[br+2][k4];
        float4 a3 = *(float4*)&At[br+3][k4];
        ACCROW(acc0, a0) ACCROW(acc1, a1) ACCROW(acc2, a2) ACCROW(acc3, a3)
    }
    float* pbase = parts + (size_t)(ks*64 + br)*NCOLS + j0 + ji*4;
    *(float4*)(pbase)           = acc0;
    *(float4*)(pbase + NCOLS)   = acc1;
    *(float4*)(pbase + 2*NCOLS) = acc2;
    *(float4*)(pbase + 3*NCOLS) = acc3;
}

// ---------------------------------------------------------------------------
// Kernel 3/5: sum partials + bias, then LayerNorm + ReLU.  grid=64 (per b).
// ---------------------------------------------------------------------------
template<int N>
__global__ __launch_bounds__(256) void reduce_ln_relu(
    const float* __restrict__ parts, const float* __restrict__ bias,
    const float* __restrict__ g, const float* __restrict__ be,
    float* __restrict__ out, int KS)
{
    constexpr int NV = N/1024;      // float4 per thread
    const int b = blockIdx.x, t = threadIdx.x;
    float4 acc[NV];
    #pragma unroll
    for (int v = 0; v < NV; ++v)
        acc[v] = *(const float4*)(bias + v*1024 + t*4);
    for (int ks = 0; ks < KS; ++ks) {
        const float* p = parts + (size_t)(ks*64 + b)*N;
        #pragma unroll
        for (int v = 0; v < NV; ++v) {
            float4 q = *(const float4*)(p + v*1024 + t*4);
            acc[v].x += q.x; acc[v].y += q.y; acc[v].z += q.z; acc[v].w += q.w;
        }
    }
    float s = 0.f, s2 = 0.f;
    #pragma unroll
    for (int v = 0; v < NV; ++v) {
        s  += acc[v].x + acc[v].y + acc[v].z + acc[v].w;
        s2 += acc[v].x*acc[v].x + acc[v].y*acc[v].y +
              acc[v].z*acc[v].z + acc[v].w*acc[v].w;
    }
    #pragma unroll
    for (int off = 32; off > 0; off >>= 1) {
        s  += __shfl_down(s,  off);
        s2 += __shfl_down(s2, off);
    }
    __shared__ float red[2][4];
    const int w = t >> 6;
    if ((t & 63) == 0) { red[0][w] = s; red[1][w] = s2; }
    __syncthreads();
    float ts  = red[0][0] + red[0][1] + red[0][2] + red[0][3];
    float ts2 = red[1][0] + red[1][1] + red[1][2] + red[1][3];
    const float inv_n = 1.0f/(float)N;
    float mu  = ts*inv_n;
    float var = ts2*inv_n - mu*mu;
    float rs  = rsqrtf(var + 1e-5f);
    #pragma unroll
    for (int v = 0; v < NV; ++v) {
        const int j = v*1024 + t*4;
        float4 gv  = *(const float4*)(g + j);
        float4 bev = *(const float4*)(be + j);
        float4 o;
        o.x = fmaxf((acc[v].x - mu)*rs*gv.x + bev.x, 0.f);
        o.y = fmaxf((acc[v].y - mu)*rs*gv.y + bev.y, 0.f);
        o.z = fmaxf((acc[v].z - mu)*rs*gv.z + bev.z, 0.f);
        o.w = fmaxf((acc[v].w - mu)*rs*gv.w + bev.w, 0.f);
        *(float4*)(out + (size_t)b*N + j) = o;
    }
}

// ---------------------------------------------------------------------------
// Kernel 6: out[b,s,:] = h2[b, s*8 .. s*8+7] @ W3 + b3 -> [64,512,4096] f32
// grid = (512 row-groups of 64 rows, 4 j-slices of 1024), block 256.
// h2 reads wave-uniform -> s_load (K$); W3 in registers; NT float4 stores.
// ---------------------------------------------------------------------------
#define ROWS_D 64
__global__ __launch_bounds__(256) void final_mm(
    const float* __restrict__ h2, const float* __restrict__ W3,
    const float* __restrict__ b3, float* __restrict__ out)
{
    const int rg = blockIdx.x;
    const int js = blockIdx.y;
    const int t  = threadIdx.x;
    const int bs0 = rg*ROWS_D;
    const int j = js*1024 + t*4;
    float4 w[8];
    #pragma unroll
    for (int k = 0; k < 8; ++k) w[k] = *(const float4*)(W3 + k*4096 + j);
    const float4 bv = *(const float4*)(b3 + j);
    const float* __restrict__ hrow = h2 + (size_t)bs0*8;
    float* __restrict__ obase = out + (size_t)bs0*4096 + j;
    #pragma unroll 4
    for (int r = 0; r < ROWS_D; ++r) {
        float4 acc = bv;
        #pragma unroll
        for (int k = 0; k < 8; ++k) {
            const float hv = hrow[r*8 + k];   // wave-uniform -> s_load (K$)
            acc.x += hv*w[k].x; acc.y += hv*w[k].y;
            acc.z += hv*w[k].z; acc.w += hv*w[k].w;
        }
        nt_store4(acc, obase + (size_t)r*4096);
    }
}

// ---------------------------------------------------------------------------
extern "C" void kernel_launch(void* const* d_in, const int* in_sizes, int n_in,
                              void* d_out, int out_size, void* d_ws, size_t ws_size,
                              hipStream_t stream) {
    const float* x      = (const float*)d_in[0];
    const float* enc_W  = (const float*)d_in[1];
    const float* enc_b  = (const float*)d_in[2];
    const float* ln_s   = (const float*)d_in[3];
    const float* ln_b   = (const float*)d_in[4];
    const float* log_dt = (const float*)d_in[5];
    const float* A_re   = (const float*)d_in[6];
    const float* A_im   = (const float*)d_in[7];
    const float* C_re   = (const float*)d_in[8];
    const float* C_im   = (const float*)d_in[9];
    const float* Dp     = (const float*)d_in[10];
    const float* out_W  = (const float*)d_in[11];
    const float* out_b  = (const float*)d_in[12];
    const float* dec_W  = (const float*)d_in[13];
    const float* dec_b  = (const float*)d_in[14];
    const float* W1     = (const float*)d_in[15];
    const float* b1     = (const float*)d_in[16];
    const float* g1     = (const float*)d_in[17];
    const float* be1    = (const float*)d_in[18];
    const float* W2     = (const float*)d_in[19];
    const float* b2     = (const float*)d_in[20];
    const float* g2     = (const float*)d_in[21];
    const float* be2    = (const float*)d_in[22];
    const float* W3     = (const float*)d_in[23];
    const float* b3     = (const float*)d_in[24];
    float* out = (float*)d_out;

    float* ws = (float*)d_ws;
    float* combined = ws;                        // 64*1856
    float* parts1   = combined + 64*1856;        // 29*64*1024
    float* h1       = parts1 + 29*64*1024;       // 64*1024
    float* parts2   = h1 + 64*1024;              // 16*64*4096
    float* h2       = parts2 + 16*64*4096;       // 64*4096

    s4front<<<64, 1024, 0, stream>>>(x, enc_W, enc_b, ln_s, ln_b, log_dt,
                                     A_re, A_im, C_re, C_im, Dp,
                                     out_W, out_b, dec_W, dec_b, combined);
    mlp_part<1024,1856,64><<<dim3(29,16), 256, 0, stream>>>(combined, W1, parts1);
    reduce_ln_relu<1024><<<64, 256, 0, stream>>>(parts1, b1, g1, be1, h1, 29);
    mlp_part<4096,1024,64><<<dim3(16,64), 256, 0, stream>>>(h1, W2, parts2);
    reduce_ln_relu<4096><<<64, 256, 0, stream>>>(parts2, b2, g2, be2, h2, 16);
    final_mm<<<dim3(512,4), 256, 0, stream>>>(h2, W3, b3, out);
}